// Round 1
// baseline (139.403 us; speedup 1.0000x reference)
//
#include <hip/hip_runtime.h>
#include <hip/hip_bf16.h>

#define S_DIM 1024
#define B_DIM 64
#define A_DIM 1024   // D_ALIGN = D_DEC = D_ENC = 1024

// ---------------------------------------------------------------------------
// Kernel 1: split-K GEMM partials   part[kz][a][b] = sum_{k in chunk} s_tm1[b,k]*sa_w[a,k]
// M=64 (b), N=1024 (a), K=1024 split into 16 chunks of 64.
// ---------------------------------------------------------------------------
#define K_TILE 64
#define KSPLIT 16
#define A_TILE 64

__global__ __launch_bounds__(256) void gemm_partial_kernel(
    const float* __restrict__ s_tm1,   // [B][1024]
    const float* __restrict__ sa_w,    // [1024][1024]
    float* __restrict__ part)          // [KSPLIT][1024][B]
{
    __shared__ float sW[K_TILE][68];   // [k][a_local], pad 68 keeps 16B align + breaks conflicts
    __shared__ float sS[K_TILE][68];   // [k][b]
    const int a0 = blockIdx.x * A_TILE;
    const int k0 = blockIdx.y * K_TILE;
    const int t  = threadIdx.x;

    // Stage both 64x64 tiles (transposed to [k][row]) with float4 global loads.
    #pragma unroll
    for (int i = 0; i < 4; ++i) {
        int idx = t + 256 * i;          // 0..1023 float4 slots
        int row = idx >> 4;             // 16 float4 per row
        int c4  = (idx & 15) * 4;       // k offset
        float4 v = *(const float4*)(sa_w + (size_t)(a0 + row) * 1024 + k0 + c4);
        sW[c4 + 0][row] = v.x; sW[c4 + 1][row] = v.y;
        sW[c4 + 2][row] = v.z; sW[c4 + 3][row] = v.w;
        float4 u = *(const float4*)(s_tm1 + (size_t)row * 1024 + k0 + c4);
        sS[c4 + 0][row] = u.x; sS[c4 + 1][row] = u.y;
        sS[c4 + 2][row] = u.z; sS[c4 + 3][row] = u.w;
    }
    __syncthreads();

    const int ta = (t & 15) * 4;        // a_local base (4 a's)
    const int tb = (t >> 4) * 4;        // b base (4 b's)
    float acc[4][4] = {};
    #pragma unroll 8
    for (int k = 0; k < K_TILE; ++k) {
        float4 wa = *(const float4*)&sW[k][ta];
        float4 sb = *(const float4*)&sS[k][tb];
        float wv[4] = {wa.x, wa.y, wa.z, wa.w};
        float sv[4] = {sb.x, sb.y, sb.z, sb.w};
        #pragma unroll
        for (int i = 0; i < 4; ++i)
            #pragma unroll
            for (int j = 0; j < 4; ++j)
                acc[i][j] += wv[i] * sv[j];
    }

    float* outp = part + (size_t)blockIdx.y * (1024 * B_DIM);
    #pragma unroll
    for (int i = 0; i < 4; ++i)
        #pragma unroll
        for (int j = 0; j < 4; ++j)
            outp[(size_t)(a0 + ta + i) * B_DIM + (tb + j)] = acc[i][j];
}

// ---------------------------------------------------------------------------
// Kernel 1b: sa_s[b][a] = sa_b[a] + sum_kz part[kz][a][b]
// ---------------------------------------------------------------------------
__global__ __launch_bounds__(256) void gemm_reduce_kernel(
    const float* __restrict__ part, const float* __restrict__ sa_b,
    float* __restrict__ sa_s)          // [B][1024]
{
    int b = blockIdx.x, t = threadIdx.x;
    #pragma unroll
    for (int i = 0; i < 4; ++i) {
        int a = t + 256 * i;
        float s = sa_b[a];
        #pragma unroll
        for (int kz = 0; kz < KSPLIT; ++kz)
            s += part[(size_t)kz * 65536 + (size_t)a * B_DIM + b];
        sa_s[(size_t)b * 1024 + a] = s;
    }
}

// ---------------------------------------------------------------------------
// Kernel 2: e[s*64+b] = a1_b + sum_a tanh(sa_s[b,a] + uh[s,b,a]) * a1_w[a]
// One wave per (s,b) row; coalesced float4 stream over uh (256 MiB).
// ---------------------------------------------------------------------------
__device__ __forceinline__ float fast_tanh(float x) {
    float ax = __builtin_fabsf(x);
    float t  = __expf(-2.0f * ax);               // in (0,1], no overflow
    float r  = __fdividef(1.0f - t, 1.0f + t);   // tanh(|x|)
    return __builtin_copysignf(r, x);
}

__global__ __launch_bounds__(256) void e_kernel(
    const float* __restrict__ uh,      // [S][B][1024]
    const float* __restrict__ sa_s,    // [B][1024]
    const float* __restrict__ a1_w,    // [1024]
    const float* __restrict__ a1_b,    // [1]
    float* __restrict__ e_out)         // [S][B]
{
    const int lane = threadIdx.x & 63;
    const int w    = threadIdx.x >> 6;
    const int p    = blockIdx.x * 4 + w;          // p = s*64 + b
    const int b    = p & 63;

    const float4* uhp = (const float4*)(uh + (size_t)p * 1024);
    const float4* sap = (const float4*)(sa_s + (size_t)b * 1024);
    const float4* awp = (const float4*)a1_w;

    float acc = 0.f;
    #pragma unroll
    for (int i = 0; i < 4; ++i) {
        int idx = lane + 64 * i;                  // 0..255 float4 slots
        float4 u  = uhp[idx];
        float4 sv = sap[idx];
        float4 aw = awp[idx];
        acc += fast_tanh(u.x + sv.x) * aw.x;
        acc += fast_tanh(u.y + sv.y) * aw.y;
        acc += fast_tanh(u.z + sv.z) * aw.z;
        acc += fast_tanh(u.w + sv.w) * aw.w;
    }
    #pragma unroll
    for (int off = 32; off; off >>= 1) acc += __shfl_xor(acc, off);
    if (lane == 0) e_out[p] = acc + a1_b[0];
}

// ---------------------------------------------------------------------------
// Kernel 3: masked softmax over s for each b; writes e_ij straight to d_out.
// ---------------------------------------------------------------------------
__global__ __launch_bounds__(256) void softmax_kernel(
    const float* __restrict__ e,       // [S][B]
    const float* __restrict__ mask,    // [S][B]
    float* __restrict__ eij)           // [S][B] (d_out)
{
    const int b = blockIdx.x;
    const int t = threadIdx.x;
    const int lane = t & 63, w = t >> 6;
    __shared__ float red[4];

    float v[4];
    float mx = -1e30f;
    #pragma unroll
    for (int i = 0; i < 4; ++i) {
        v[i] = e[(size_t)(t + 256 * i) * B_DIM + b];
        mx = fmaxf(mx, v[i]);
    }
    #pragma unroll
    for (int off = 32; off; off >>= 1) mx = fmaxf(mx, __shfl_xor(mx, off));
    if (lane == 0) red[w] = mx;
    __syncthreads();
    mx = fmaxf(fmaxf(red[0], red[1]), fmaxf(red[2], red[3]));
    __syncthreads();

    float ex[4];
    float sum = 0.f;
    #pragma unroll
    for (int i = 0; i < 4; ++i) {
        ex[i] = __expf(v[i] - mx) * mask[(size_t)(t + 256 * i) * B_DIM + b];
        sum += ex[i];
    }
    #pragma unroll
    for (int off = 32; off; off >>= 1) sum += __shfl_xor(sum, off);
    if (lane == 0) red[w] = sum;
    __syncthreads();
    float inv = 1.0f / (red[0] + red[1] + red[2] + red[3]);
    #pragma unroll
    for (int i = 0; i < 4; ++i)
        eij[(size_t)(t + 256 * i) * B_DIM + b] = ex[i] * inv;
}

// ---------------------------------------------------------------------------
// Kernel 4: attend partials over s-chunks: part[sz][b][d] (split-S, no atomics)
// ---------------------------------------------------------------------------
#define SSPLIT 16
#define S_CHUNK 64

__global__ __launch_bounds__(256) void attend_partial_kernel(
    const float* __restrict__ xs_h,    // [S][B][1024]
    const float* __restrict__ eij,     // [S][B] (d_out)
    float* __restrict__ part)          // [SSPLIT][B][1024]
{
    const int b  = blockIdx.x;
    const int sz = blockIdx.y;
    const int t  = threadIdx.x;        // owns d = 4t..4t+3
    const int s0 = sz * S_CHUNK;

    float4 acc = {0.f, 0.f, 0.f, 0.f};
    #pragma unroll 8
    for (int s = s0; s < s0 + S_CHUNK; ++s) {
        float wgt = eij[(size_t)s * B_DIM + b];
        float4 x = *(const float4*)(xs_h + ((size_t)s * B_DIM + b) * 1024 + t * 4);
        acc.x += wgt * x.x; acc.y += wgt * x.y;
        acc.z += wgt * x.z; acc.w += wgt * x.w;
    }
    ((float4*)part)[((size_t)sz * B_DIM + b) * 256 + t] = acc;
}

// ---------------------------------------------------------------------------
// Kernel 4b: attend[b][d] = sum_sz part[sz][b][d]  -> d_out + S*B
// ---------------------------------------------------------------------------
__global__ __launch_bounds__(256) void attend_reduce_kernel(
    const float* __restrict__ part, float* __restrict__ out)
{
    int idx = blockIdx.x * 256 + threadIdx.x;   // 0..65535 over [b][d]
    float s = 0.f;
    #pragma unroll
    for (int sz = 0; sz < SSPLIT; ++sz)
        s += part[(size_t)sz * 65536 + idx];
    out[idx] = s;
}

// ---------------------------------------------------------------------------
extern "C" void kernel_launch(void* const* d_in, const int* in_sizes, int n_in,
                              void* d_out, int out_size, void* d_ws, size_t ws_size,
                              hipStream_t stream) {
    const float* s_tm1   = (const float*)d_in[0];  // [64][1024]
    const float* xs_h    = (const float*)d_in[1];  // [1024][64][1024]
    const float* uh      = (const float*)d_in[2];  // [1024][64][1024]
    const float* xs_mask = (const float*)d_in[3];  // [1024][64]
    const float* sa_w    = (const float*)d_in[4];  // [1024][1024]
    const float* sa_b    = (const float*)d_in[5];  // [1024]
    const float* a1_w    = (const float*)d_in[6];  // [1][1024]
    const float* a1_b    = (const float*)d_in[7];  // [1]

    float* eij_out = (float*)d_out;                // [S][B] = 65536
    float* att_out = (float*)d_out + S_DIM * B_DIM;// [B][1024] = 65536

    float* part_gemm = (float*)d_ws;                               // 16*1024*64   = 1M floats
    float* sa_s      = part_gemm + (size_t)KSPLIT * 1024 * B_DIM;  // 64*1024
    float* e_buf     = sa_s + 65536;                               // 1024*64
    float* part_att  = e_buf + 65536;                              // 16*64*1024   = 1M floats

    gemm_partial_kernel<<<dim3(A_DIM / A_TILE, KSPLIT), 256, 0, stream>>>(s_tm1, sa_w, part_gemm);
    gemm_reduce_kernel<<<B_DIM, 256, 0, stream>>>(part_gemm, sa_b, sa_s);
    e_kernel<<<S_DIM * B_DIM / 4, 256, 0, stream>>>(uh, sa_s, a1_w, a1_b, e_buf);
    softmax_kernel<<<B_DIM, 256, 0, stream>>>(e_buf, xs_mask, eij_out);
    attend_partial_kernel<<<dim3(B_DIM, SSPLIT), 256, 0, stream>>>(xs_h, eij_out, part_att);
    attend_reduce_kernel<<<65536 / 256, 256, 0, stream>>>(part_att, att_out);
}

// Round 2
// 135.525 us; speedup vs baseline: 1.0286x; 1.0286x over previous
//
#include <hip/hip_runtime.h>
#include <hip/hip_bf16.h>

#define S_DIM 1024
#define B_DIM 64
#define A_DIM 1024   // D_ALIGN = D_DEC = D_ENC = 1024

// K2 = 2 * log2(e): tanh(x) = 1 - 2/(exp2(K2*x)+1)
#define K2_CONST 2.8853900817779268f

// ---------------------------------------------------------------------------
// Kernel 1: split-K GEMM partials   part[kz][a][b] = sum_{k in chunk} s_tm1[b,k]*sa_w[a,k]
// ---------------------------------------------------------------------------
#define K_TILE 64
#define KSPLIT 16
#define A_TILE 64

__global__ __launch_bounds__(256) void gemm_partial_kernel(
    const float* __restrict__ s_tm1,   // [B][1024]
    const float* __restrict__ sa_w,    // [1024][1024]
    float* __restrict__ part)          // [KSPLIT][1024][B]
{
    __shared__ float sW[K_TILE][68];
    __shared__ float sS[K_TILE][68];
    const int a0 = blockIdx.x * A_TILE;
    const int k0 = blockIdx.y * K_TILE;
    const int t  = threadIdx.x;

    #pragma unroll
    for (int i = 0; i < 4; ++i) {
        int idx = t + 256 * i;
        int row = idx >> 4;
        int c4  = (idx & 15) * 4;
        float4 v = *(const float4*)(sa_w + (size_t)(a0 + row) * 1024 + k0 + c4);
        sW[c4 + 0][row] = v.x; sW[c4 + 1][row] = v.y;
        sW[c4 + 2][row] = v.z; sW[c4 + 3][row] = v.w;
        float4 u = *(const float4*)(s_tm1 + (size_t)row * 1024 + k0 + c4);
        sS[c4 + 0][row] = u.x; sS[c4 + 1][row] = u.y;
        sS[c4 + 2][row] = u.z; sS[c4 + 3][row] = u.w;
    }
    __syncthreads();

    const int ta = (t & 15) * 4;
    const int tb = (t >> 4) * 4;
    float acc[4][4] = {};
    #pragma unroll 8
    for (int k = 0; k < K_TILE; ++k) {
        float4 wa = *(const float4*)&sW[k][ta];
        float4 sb = *(const float4*)&sS[k][tb];
        float wv[4] = {wa.x, wa.y, wa.z, wa.w};
        float sv[4] = {sb.x, sb.y, sb.z, sb.w};
        #pragma unroll
        for (int i = 0; i < 4; ++i)
            #pragma unroll
            for (int j = 0; j < 4; ++j)
                acc[i][j] += wv[i] * sv[j];
    }

    float* outp = part + (size_t)blockIdx.y * (1024 * B_DIM);
    #pragma unroll
    for (int i = 0; i < 4; ++i)
        #pragma unroll
        for (int j = 0; j < 4; ++j)
            outp[(size_t)(a0 + ta + i) * B_DIM + (tb + j)] = acc[i][j];
}

// ---------------------------------------------------------------------------
// Kernel 1b: ksa[b][a] = K2 * (sa_b[a] + sum_kz part[kz][a][b])   (pre-scaled)
// ---------------------------------------------------------------------------
__global__ __launch_bounds__(256) void gemm_reduce_kernel(
    const float* __restrict__ part, const float* __restrict__ sa_b,
    float* __restrict__ ksa)           // [B][1024]
{
    int b = blockIdx.x, t = threadIdx.x;
    #pragma unroll
    for (int i = 0; i < 4; ++i) {
        int a = t + 256 * i;
        float s = sa_b[a];
        #pragma unroll
        for (int kz = 0; kz < KSPLIT; ++kz)
            s += part[(size_t)kz * 65536 + (size_t)a * B_DIM + b];
        ksa[(size_t)b * 1024 + a] = K2_CONST * s;
    }
}

// ---------------------------------------------------------------------------
// Kernel 2: e'[b][s] = -2 * sum_a a1_w[a] * rcp(1 + exp2(K2*uh[s,b,a] + ksa[b,a]))
// (equals e[s,b] up to a per-column-constant shift, which softmax cancels)
// One wave per (s,b) row; coalesced float4 stream over uh (256 MiB).
// ---------------------------------------------------------------------------
__device__ __forceinline__ float fast_exp2(float x) {
#if __has_builtin(__builtin_amdgcn_exp2f)
    return __builtin_amdgcn_exp2f(x);
#else
    return exp2f(x);
#endif
}

__global__ __launch_bounds__(256) void e_kernel(
    const float* __restrict__ uh,      // [S][B][1024]
    const float* __restrict__ ksa,     // [B][1024]  (pre-scaled by K2)
    const float* __restrict__ a1_w,    // [1024]
    float* __restrict__ e_out)         // [B][S]  (transposed)
{
    const int lane = threadIdx.x & 63;
    const int w    = threadIdx.x >> 6;
    const int p    = blockIdx.x * 4 + w;          // p = s*64 + b
    const int b    = p & 63;
    const int s    = p >> 6;

    const float4* uhp = (const float4*)(uh + (size_t)p * 1024);
    const float4* sap = (const float4*)(ksa + (size_t)b * 1024);
    const float4* awp = (const float4*)a1_w;

    float acc = 0.f;
    #pragma unroll
    for (int i = 0; i < 4; ++i) {
        int idx = lane + 64 * i;                  // 0..255 float4 slots
        float4 u  = uhp[idx];
        float4 sv = sap[idx];
        float4 aw = awp[idx];
        float t0 = fast_exp2(fmaf(K2_CONST, u.x, sv.x));
        float t1 = fast_exp2(fmaf(K2_CONST, u.y, sv.y));
        float t2 = fast_exp2(fmaf(K2_CONST, u.z, sv.z));
        float t3 = fast_exp2(fmaf(K2_CONST, u.w, sv.w));
        acc = fmaf(aw.x, __builtin_amdgcn_rcpf(1.0f + t0), acc);
        acc = fmaf(aw.y, __builtin_amdgcn_rcpf(1.0f + t1), acc);
        acc = fmaf(aw.z, __builtin_amdgcn_rcpf(1.0f + t2), acc);
        acc = fmaf(aw.w, __builtin_amdgcn_rcpf(1.0f + t3), acc);
    }
    #pragma unroll
    for (int off = 32; off; off >>= 1) acc += __shfl_xor(acc, off);
    if (lane == 0) e_out[(size_t)b * S_DIM + s] = -2.0f * acc;
}

// ---------------------------------------------------------------------------
// Kernel 3: masked softmax over s for each b; reads transposed e, writes [S][B].
// ---------------------------------------------------------------------------
__global__ __launch_bounds__(256) void softmax_kernel(
    const float* __restrict__ e,       // [B][S] (transposed)
    const float* __restrict__ mask,    // [S][B]
    float* __restrict__ eij)           // [S][B] (d_out)
{
    const int b = blockIdx.x;
    const int t = threadIdx.x;
    const int lane = t & 63, w = t >> 6;
    __shared__ float red[4];

    float v[4];
    float mx = -1e30f;
    #pragma unroll
    for (int i = 0; i < 4; ++i) {
        v[i] = e[(size_t)b * S_DIM + t + 256 * i];
        mx = fmaxf(mx, v[i]);
    }
    #pragma unroll
    for (int off = 32; off; off >>= 1) mx = fmaxf(mx, __shfl_xor(mx, off));
    if (lane == 0) red[w] = mx;
    __syncthreads();
    mx = fmaxf(fmaxf(red[0], red[1]), fmaxf(red[2], red[3]));
    __syncthreads();

    float ex[4];
    float sum = 0.f;
    #pragma unroll
    for (int i = 0; i < 4; ++i) {
        ex[i] = __expf(v[i] - mx) * mask[(size_t)(t + 256 * i) * B_DIM + b];
        sum += ex[i];
    }
    #pragma unroll
    for (int off = 32; off; off >>= 1) sum += __shfl_xor(sum, off);
    if (lane == 0) red[w] = sum;
    __syncthreads();
    float inv = 1.0f / (red[0] + red[1] + red[2] + red[3]);
    #pragma unroll
    for (int i = 0; i < 4; ++i)
        eij[(size_t)(t + 256 * i) * B_DIM + b] = ex[i] * inv;
}

// ---------------------------------------------------------------------------
// Kernel 4: attend partials over s-chunks: part[sz][b][d] (split-S, no atomics)
// ---------------------------------------------------------------------------
#define SSPLIT 16
#define S_CHUNK 64

__global__ __launch_bounds__(256) void attend_partial_kernel(
    const float* __restrict__ xs_h,    // [S][B][1024]
    const float* __restrict__ eij,     // [S][B] (d_out)
    float* __restrict__ part)          // [SSPLIT][B][1024]
{
    const int b  = blockIdx.x;
    const int sz = blockIdx.y;
    const int t  = threadIdx.x;        // owns d = 4t..4t+3
    const int s0 = sz * S_CHUNK;

    __shared__ float se[S_CHUNK];
    if (t < S_CHUNK) se[t] = eij[(size_t)(s0 + t) * B_DIM + b];
    __syncthreads();

    float4 acc = {0.f, 0.f, 0.f, 0.f};
    #pragma unroll 8
    for (int i = 0; i < S_CHUNK; ++i) {
        float wgt = se[i];
        float4 x = *(const float4*)(xs_h + ((size_t)(s0 + i) * B_DIM + b) * 1024 + t * 4);
        acc.x = fmaf(wgt, x.x, acc.x); acc.y = fmaf(wgt, x.y, acc.y);
        acc.z = fmaf(wgt, x.z, acc.z); acc.w = fmaf(wgt, x.w, acc.w);
    }
    ((float4*)part)[((size_t)sz * B_DIM + b) * 256 + t] = acc;
}

// ---------------------------------------------------------------------------
// Kernel 4b: attend[b][d] = sum_sz part[sz][b][d]  -> d_out + S*B
// ---------------------------------------------------------------------------
__global__ __launch_bounds__(256) void attend_reduce_kernel(
    const float* __restrict__ part, float* __restrict__ out)
{
    int idx = blockIdx.x * 256 + threadIdx.x;
    float s = 0.f;
    #pragma unroll
    for (int sz = 0; sz < SSPLIT; ++sz)
        s += part[(size_t)sz * 65536 + idx];
    out[idx] = s;
}

// ---------------------------------------------------------------------------
extern "C" void kernel_launch(void* const* d_in, const int* in_sizes, int n_in,
                              void* d_out, int out_size, void* d_ws, size_t ws_size,
                              hipStream_t stream) {
    const float* s_tm1   = (const float*)d_in[0];  // [64][1024]
    const float* xs_h    = (const float*)d_in[1];  // [1024][64][1024]
    const float* uh      = (const float*)d_in[2];  // [1024][64][1024]
    const float* xs_mask = (const float*)d_in[3];  // [1024][64]
    const float* sa_w    = (const float*)d_in[4];  // [1024][1024]
    const float* sa_b    = (const float*)d_in[5];  // [1024]
    const float* a1_w    = (const float*)d_in[6];  // [1][1024]
    // d_in[7] = a1_b: constant shift, cancels in softmax; attend unaffected.

    float* eij_out = (float*)d_out;                // [S][B] = 65536
    float* att_out = (float*)d_out + S_DIM * B_DIM;// [B][1024] = 65536

    float* part_gemm = (float*)d_ws;                               // 16*1024*64
    float* ksa       = part_gemm + (size_t)KSPLIT * 1024 * B_DIM;  // 64*1024
    float* e_buf     = ksa + 65536;                                // [B][S]
    float* part_att  = e_buf + 65536;                              // 16*64*1024

    gemm_partial_kernel<<<dim3(A_DIM / A_TILE, KSPLIT), 256, 0, stream>>>(s_tm1, sa_w, part_gemm);
    gemm_reduce_kernel<<<B_DIM, 256, 0, stream>>>(part_gemm, sa_b, ksa);
    e_kernel<<<S_DIM * B_DIM / 4, 256, 0, stream>>>(uh, ksa, a1_w, e_buf);
    softmax_kernel<<<B_DIM, 256, 0, stream>>>(e_buf, xs_mask, eij_out);
    attend_partial_kernel<<<dim3(B_DIM, SSPLIT), 256, 0, stream>>>(xs_h, eij_out, part_att);
    attend_reduce_kernel<<<65536 / 256, 256, 0, stream>>>(part_att, att_out);
}

// Round 3
// 114.080 us; speedup vs baseline: 1.2220x; 1.1880x over previous
//
#include <hip/hip_runtime.h>
#include <hip/hip_bf16.h>

#define S_DIM 1024
#define B_DIM 64
#define A_DIM 1024

// K2 = 2*log2(e): tanh(x) = 1 - 2/(exp2(K2*x)+1)
#define K2_CONST 2.8853900817779268f

#define K_TILE 64
#define KSPLIT 16
#define A_TILE 64
#define SSPLIT 16
#define S_CHUNK 64

__device__ __forceinline__ float fast_exp2(float x) { return __builtin_amdgcn_exp2f(x); }
__device__ __forceinline__ float fast_rcp(float x)  { return __builtin_amdgcn_rcpf(x); }

// ---------------------------------------------------------------------------
// Kernel 1: split-K GEMM partials   part[kz][b][a] = sum_{k in chunk} s_tm1[b,k]*sa_w[a,k]
// ---------------------------------------------------------------------------
__global__ __launch_bounds__(256) void gemm_partial_kernel(
    const float* __restrict__ s_tm1,   // [B][1024]
    const float* __restrict__ sa_w,    // [1024][1024]
    float* __restrict__ part)          // [KSPLIT][B][1024]
{
    __shared__ float sW[K_TILE][68];   // [k][a_local]
    __shared__ float sS[K_TILE][68];   // [k][b]
    const int a0 = blockIdx.x * A_TILE;
    const int k0 = blockIdx.y * K_TILE;
    const int t  = threadIdx.x;

    #pragma unroll
    for (int i = 0; i < 4; ++i) {
        int idx = t + 256 * i;
        int row = idx >> 4;
        int c4  = (idx & 15) * 4;
        float4 v = *(const float4*)(sa_w + (size_t)(a0 + row) * 1024 + k0 + c4);
        sW[c4 + 0][row] = v.x; sW[c4 + 1][row] = v.y;
        sW[c4 + 2][row] = v.z; sW[c4 + 3][row] = v.w;
        float4 u = *(const float4*)(s_tm1 + (size_t)row * 1024 + k0 + c4);
        sS[c4 + 0][row] = u.x; sS[c4 + 1][row] = u.y;
        sS[c4 + 2][row] = u.z; sS[c4 + 3][row] = u.w;
    }
    __syncthreads();

    const int ta = (t & 15) * 4;       // a_local base
    const int tb = (t >> 4) * 4;       // b base
    float acc[4][4] = {};
    #pragma unroll 8
    for (int k = 0; k < K_TILE; ++k) {
        float4 wa = *(const float4*)&sW[k][ta];
        float4 sb = *(const float4*)&sS[k][tb];
        float wv[4] = {wa.x, wa.y, wa.z, wa.w};
        float sv[4] = {sb.x, sb.y, sb.z, sb.w};
        #pragma unroll
        for (int i = 0; i < 4; ++i)
            #pragma unroll
            for (int j = 0; j < 4; ++j)
                acc[i][j] = fmaf(wv[i], sv[j], acc[i][j]);
    }

    // part[kz][b][a]: coalesced float4 stores along a
    float* outp = part + (size_t)blockIdx.y * (B_DIM * 1024);
    #pragma unroll
    for (int j = 0; j < 4; ++j) {
        float4 v = {acc[0][j], acc[1][j], acc[2][j], acc[3][j]};
        *(float4*)(outp + (size_t)(tb + j) * 1024 + a0 + ta) = v;
    }
}

// ---------------------------------------------------------------------------
// Kernel 1b: ksa[b][a] = K2 * (sa_b[a] + sum_kz part[kz][b][a])   (coalesced)
// ---------------------------------------------------------------------------
__global__ __launch_bounds__(256) void gemm_reduce_kernel(
    const float* __restrict__ part, const float* __restrict__ sa_b,
    float* __restrict__ ksa)           // [B][1024]
{
    int idx = blockIdx.x * 256 + threadIdx.x;   // over [B][1024]
    int a = idx & 1023;
    float s = sa_b[a];
    #pragma unroll
    for (int kz = 0; kz < KSPLIT; ++kz)
        s += part[(size_t)kz * 65536 + idx];
    ksa[idx] = K2_CONST * s;
}

// ---------------------------------------------------------------------------
// Kernel 2 (fused): per (b, s-chunk):
//  phase 1: ex[s] = exp2(-K2 * sum_a a1_w[a]*rcp(1+exp2(K2*uh+ksa))) * mask
//  phase 2: part[sz][b][d] = sum_{s in chunk} ex[s]*xs_h[s,b,d];  psum[sz][b]=sum ex
// ---------------------------------------------------------------------------
__global__ __launch_bounds__(256) void fused_kernel(
    const float* __restrict__ uh,      // [S][B][1024]
    const float* __restrict__ xs_h,    // [S][B][1024]
    const float* __restrict__ ksa,     // [B][1024] (pre-scaled by K2)
    const float* __restrict__ a1_w,    // [1024]
    const float* __restrict__ xs_mask, // [S][B]
    float* __restrict__ ex_buf,        // [S][B] (unnormalized masked ex)
    float* __restrict__ psum,          // [SSPLIT][B]
    float* __restrict__ part)          // [SSPLIT][B][1024]
{
    const int b    = blockIdx.x;
    const int sz   = blockIdx.y;
    const int s0   = sz * S_CHUNK;
    const int t    = threadIdx.x;
    const int lane = t & 63;
    const int w    = t >> 6;

    __shared__ float s_ex[S_CHUNK];

    // block-invariant fragments -> registers (uh is then the only big stream)
    const float4* sap = (const float4*)(ksa + (size_t)b * 1024);
    const float4* awp = (const float4*)a1_w;
    float4 sv[4], aw[4];
    #pragma unroll
    for (int j = 0; j < 4; ++j) { sv[j] = sap[lane + 64 * j]; aw[j] = awp[lane + 64 * j]; }

    // phase 1: wave w reduces rows {w, w+4, ..., w+60}
    for (int k = 0; k < 16; ++k) {
        const int i = w + 4 * k;
        const int s = s0 + i;
        const float4* uhp = (const float4*)(uh + ((size_t)s * B_DIM + b) * 1024);
        float mrow = xs_mask[(size_t)s * B_DIM + b];
        float acc = 0.f;
        #pragma unroll
        for (int j = 0; j < 4; ++j) {
            float4 u = uhp[lane + 64 * j];
            float t0 = fast_exp2(fmaf(K2_CONST, u.x, sv[j].x));
            float t1 = fast_exp2(fmaf(K2_CONST, u.y, sv[j].y));
            float t2 = fast_exp2(fmaf(K2_CONST, u.z, sv[j].z));
            float t3 = fast_exp2(fmaf(K2_CONST, u.w, sv[j].w));
            acc = fmaf(aw[j].x, fast_rcp(1.0f + t0), acc);
            acc = fmaf(aw[j].y, fast_rcp(1.0f + t1), acc);
            acc = fmaf(aw[j].z, fast_rcp(1.0f + t2), acc);
            acc = fmaf(aw[j].w, fast_rcp(1.0f + t3), acc);
        }
        #pragma unroll
        for (int off = 32; off; off >>= 1) acc += __shfl_xor(acc, off);
        if (lane == 0) s_ex[i] = fast_exp2(-K2_CONST * acc) * mrow;  // e2 = log2e * e'
    }
    __syncthreads();

    // phase 2: thread owns d = 4t..4t+3; stream xs_h rows of this chunk
    float4 acc4 = {0.f, 0.f, 0.f, 0.f};
    #pragma unroll 8
    for (int i = 0; i < S_CHUNK; ++i) {
        float wgt = s_ex[i];
        float4 x = *(const float4*)(xs_h + (((size_t)(s0 + i) * B_DIM + b) * 1024) + t * 4);
        acc4.x = fmaf(wgt, x.x, acc4.x); acc4.y = fmaf(wgt, x.y, acc4.y);
        acc4.z = fmaf(wgt, x.z, acc4.z); acc4.w = fmaf(wgt, x.w, acc4.w);
    }
    ((float4*)part)[((size_t)sz * B_DIM + b) * 256 + t] = acc4;

    if (t < S_CHUNK)
        ex_buf[(size_t)(s0 + t) * B_DIM + b] = s_ex[t];

    if (w == 0) {   // psum over the chunk (s_ex stable since barrier)
        float v = s_ex[lane];
        #pragma unroll
        for (int off = 32; off; off >>= 1) v += __shfl_xor(v, off);
        if (lane == 0) psum[sz * B_DIM + b] = v;
    }
}

// ---------------------------------------------------------------------------
// Kernel 3 (finalize): blocks 0..255: eij = ex_buf * inv_sum[b]
//                      blocks 256..511: attend = (sum_sz part) * inv_sum[b]
// ---------------------------------------------------------------------------
__global__ __launch_bounds__(256) void finalize_kernel(
    const float* __restrict__ ex_buf, const float* __restrict__ part,
    const float* __restrict__ psum,
    float* __restrict__ eij_out, float* __restrict__ att_out)
{
    const int blk = blockIdx.x;
    const int t = threadIdx.x;
    if (blk < 256) {
        int idx = blk * 256 + t;           // over [S][B]
        int b = idx & 63;
        float ssum = 0.f;
        #pragma unroll
        for (int sz = 0; sz < SSPLIT; ++sz) ssum += psum[sz * B_DIM + b];
        eij_out[idx] = ex_buf[idx] * (1.0f / ssum);
    } else {
        int idx = (blk - 256) * 256 + t;   // over [B][1024]
        int b = idx >> 10;
        float ssum = 0.f;
        #pragma unroll
        for (int sz = 0; sz < SSPLIT; ++sz) ssum += psum[sz * B_DIM + b];
        float acc = 0.f;
        #pragma unroll
        for (int sz = 0; sz < SSPLIT; ++sz) acc += part[(size_t)sz * 65536 + idx];
        att_out[idx] = acc * (1.0f / ssum);
    }
}

// ---------------------------------------------------------------------------
extern "C" void kernel_launch(void* const* d_in, const int* in_sizes, int n_in,
                              void* d_out, int out_size, void* d_ws, size_t ws_size,
                              hipStream_t stream) {
    const float* s_tm1   = (const float*)d_in[0];  // [64][1024]
    const float* xs_h    = (const float*)d_in[1];  // [1024][64][1024]
    const float* uh      = (const float*)d_in[2];  // [1024][64][1024]
    const float* xs_mask = (const float*)d_in[3];  // [1024][64]
    const float* sa_w    = (const float*)d_in[4];  // [1024][1024]
    const float* sa_b    = (const float*)d_in[5];  // [1024]
    const float* a1_w    = (const float*)d_in[6];  // [1][1024]
    // d_in[7] = a1_b: global constant shift -> cancels in softmax.

    float* eij_out = (float*)d_out;                 // [S][B]
    float* att_out = (float*)d_out + S_DIM * B_DIM; // [B][1024]

    float* part_gemm = (float*)d_ws;                               // 16*64*1024
    float* ksa       = part_gemm + (size_t)KSPLIT * B_DIM * 1024;  // 64*1024
    float* ex_buf    = ksa + 65536;                                // [S][B]
    float* part_att  = ex_buf + 65536;                             // 16*64*1024
    float* psum      = part_att + (size_t)SSPLIT * B_DIM * 1024;   // 16*64

    gemm_partial_kernel<<<dim3(A_DIM / A_TILE, KSPLIT), 256, 0, stream>>>(s_tm1, sa_w, part_gemm);
    gemm_reduce_kernel<<<65536 / 256, 256, 0, stream>>>(part_gemm, sa_b, ksa);
    fused_kernel<<<dim3(B_DIM, SSPLIT), 256, 0, stream>>>(uh, xs_h, ksa, a1_w, xs_mask,
                                                          ex_buf, psum, part_att);
    finalize_kernel<<<512, 256, 0, stream>>>(ex_buf, part_att, psum, eij_out, att_out);
}

// Round 4
// 96.877 us; speedup vs baseline: 1.4390x; 1.1776x over previous
//
#include <hip/hip_runtime.h>
#include <hip/hip_bf16.h>

#define S_DIM 1024
#define B_DIM 64
#define A_DIM 1024

// K2 = 2*log2(e): tanh(x) = 1 - 2/(exp2(K2*x)+1)
#define K2_CONST 2.8853900817779268f

#define K_TILE 64
#define KSPLIT 16
#define A_TILE 64
#define SSPLIT 16
#define S_CHUNK 64

typedef float f4 __attribute__((ext_vector_type(4)));

__device__ __forceinline__ float fast_exp2(float x) { return __builtin_amdgcn_exp2f(x); }
__device__ __forceinline__ float fast_rcp(float x)  { return __builtin_amdgcn_rcpf(x); }

// ---------------------------------------------------------------------------
// Kernel 1: split-K GEMM partials   part[kz][b][a] = sum_{k in chunk} s_tm1[b,k]*sa_w[a,k]
// ---------------------------------------------------------------------------
__global__ __launch_bounds__(256) void gemm_partial_kernel(
    const float* __restrict__ s_tm1,   // [B][1024]
    const float* __restrict__ sa_w,    // [1024][1024]
    float* __restrict__ part)          // [KSPLIT][B][1024]
{
    __shared__ float sW[K_TILE][68];   // [k][a_local]
    __shared__ float sS[K_TILE][68];   // [k][b]
    const int a0 = blockIdx.x * A_TILE;
    const int k0 = blockIdx.y * K_TILE;
    const int t  = threadIdx.x;

    #pragma unroll
    for (int i = 0; i < 4; ++i) {
        int idx = t + 256 * i;
        int row = idx >> 4;
        int c4  = (idx & 15) * 4;
        f4 v = __builtin_nontemporal_load((const f4*)(sa_w + (size_t)(a0 + row) * 1024 + k0 + c4));
        sW[c4 + 0][row] = v.x; sW[c4 + 1][row] = v.y;
        sW[c4 + 2][row] = v.z; sW[c4 + 3][row] = v.w;
        f4 u = *(const f4*)(s_tm1 + (size_t)row * 1024 + k0 + c4);
        sS[c4 + 0][row] = u.x; sS[c4 + 1][row] = u.y;
        sS[c4 + 2][row] = u.z; sS[c4 + 3][row] = u.w;
    }
    __syncthreads();

    const int ta = (t & 15) * 4;       // a_local base
    const int tb = (t >> 4) * 4;       // b base
    float acc[4][4] = {};
    #pragma unroll 8
    for (int k = 0; k < K_TILE; ++k) {
        f4 wa = *(const f4*)&sW[k][ta];
        f4 sb = *(const f4*)&sS[k][tb];
        float wv[4] = {wa.x, wa.y, wa.z, wa.w};
        float sv[4] = {sb.x, sb.y, sb.z, sb.w};
        #pragma unroll
        for (int i = 0; i < 4; ++i)
            #pragma unroll
            for (int j = 0; j < 4; ++j)
                acc[i][j] = fmaf(wv[i], sv[j], acc[i][j]);
    }

    float* outp = part + (size_t)blockIdx.y * (B_DIM * 1024);
    #pragma unroll
    for (int j = 0; j < 4; ++j) {
        f4 v = {acc[0][j], acc[1][j], acc[2][j], acc[3][j]};
        *(f4*)(outp + (size_t)(tb + j) * 1024 + a0 + ta) = v;
    }
}

// ---------------------------------------------------------------------------
// Kernel 1b: ksa[b][a] = K2 * (sa_b[a] + sum_kz part[kz][b][a])
// ---------------------------------------------------------------------------
__global__ __launch_bounds__(256) void gemm_reduce_kernel(
    const float* __restrict__ part, const float* __restrict__ sa_b,
    float* __restrict__ ksa)           // [B][1024]
{
    int idx = blockIdx.x * 256 + threadIdx.x;   // over [B][1024]
    int a = idx & 1023;
    float s = sa_b[a];
    #pragma unroll
    for (int kz = 0; kz < KSPLIT; ++kz)
        s += part[(size_t)kz * 65536 + idx];
    ksa[idx] = K2_CONST * s;
}

// ---------------------------------------------------------------------------
// Kernel 2 (fused, row-interleaved): per (b, s-chunk) block, per row s:
//   ex = exp2(-K2 * sum_a a1_w[a]*rcp(1+exp2(K2*uh+ksa))) * mask   (wave reduce)
//   acc4[d] += ex * xs_h[s,b,d]                                    (same wave)
// uh streamed with NT loads (keep xs_h resident in the 256 MiB L3).
// ---------------------------------------------------------------------------
__global__ __launch_bounds__(256) void fused_kernel(
    const float* __restrict__ uh,      // [S][B][1024]
    const float* __restrict__ xs_h,    // [S][B][1024]
    const float* __restrict__ ksa,     // [B][1024] (pre-scaled by K2)
    const float* __restrict__ a1_w,    // [1024]
    const float* __restrict__ xs_mask, // [S][B]
    float* __restrict__ ex_buf,        // [S][B] (unnormalized masked ex)
    float* __restrict__ psum,          // [SSPLIT][B]
    float* __restrict__ part)          // [SSPLIT][B][1024]
{
    const int b    = blockIdx.x;
    const int sz   = blockIdx.y;
    const int s0   = sz * S_CHUNK;
    const int t    = threadIdx.x;
    const int lane = t & 63;
    const int w    = t >> 6;

    __shared__ float s_ex[S_CHUNK];
    __shared__ float s_mask[S_CHUNK];
    __shared__ f4 s_red[4][256];

    if (t < S_CHUNK) s_mask[t] = xs_mask[(size_t)(s0 + t) * B_DIM + b];

    // block-invariant fragments -> registers
    const f4* sap = (const f4*)(ksa + (size_t)b * 1024);
    const f4* awp = (const f4*)a1_w;
    f4 sv[4], aw[4];
    #pragma unroll
    for (int j = 0; j < 4; ++j) { sv[j] = sap[lane + 64 * j]; aw[j] = awp[lane + 64 * j]; }

    __syncthreads();

    f4 acc4[4];
    #pragma unroll
    for (int j = 0; j < 4; ++j) { acc4[j].x = 0.f; acc4[j].y = 0.f; acc4[j].z = 0.f; acc4[j].w = 0.f; }

    // wave w handles rows {w, w+4, ..., w+60}; both streams active per iteration
    #pragma unroll 2
    for (int k = 0; k < 16; ++k) {
        const int i = w + 4 * k;
        const size_t rowoff = ((size_t)(s0 + i) * B_DIM + b) * 1024;
        const f4* uhp = (const f4*)(uh + rowoff);
        const f4* xsp = (const f4*)(xs_h + rowoff);

        f4 xv[4];
        #pragma unroll
        for (int j = 0; j < 4; ++j) xv[j] = xsp[lane + 64 * j];   // cached loads

        float acc = 0.f;
        #pragma unroll
        for (int j = 0; j < 4; ++j) {
            f4 u = __builtin_nontemporal_load(&uhp[lane + 64 * j]); // NT: don't pollute L3
            float t0 = fast_exp2(fmaf(K2_CONST, u.x, sv[j].x));
            float t1 = fast_exp2(fmaf(K2_CONST, u.y, sv[j].y));
            float t2 = fast_exp2(fmaf(K2_CONST, u.z, sv[j].z));
            float t3 = fast_exp2(fmaf(K2_CONST, u.w, sv[j].w));
            acc = fmaf(aw[j].x, fast_rcp(1.0f + t0), acc);
            acc = fmaf(aw[j].y, fast_rcp(1.0f + t1), acc);
            acc = fmaf(aw[j].z, fast_rcp(1.0f + t2), acc);
            acc = fmaf(aw[j].w, fast_rcp(1.0f + t3), acc);
        }
        #pragma unroll
        for (int off = 32; off; off >>= 1) acc += __shfl_xor(acc, off);  // all lanes get sum

        float ex = fast_exp2(-K2_CONST * acc) * s_mask[i];
        if (lane == 0) s_ex[i] = ex;

        #pragma unroll
        for (int j = 0; j < 4; ++j) {
            acc4[j].x = fmaf(ex, xv[j].x, acc4[j].x);
            acc4[j].y = fmaf(ex, xv[j].y, acc4[j].y);
            acc4[j].z = fmaf(ex, xv[j].z, acc4[j].z);
            acc4[j].w = fmaf(ex, xv[j].w, acc4[j].w);
        }
    }

    // combine 4 waves' partials
    #pragma unroll
    for (int j = 0; j < 4; ++j) s_red[w][lane + 64 * j] = acc4[j];
    __syncthreads();

    f4 r = s_red[0][t];
    #pragma unroll
    for (int ww = 1; ww < 4; ++ww) {
        f4 q = s_red[ww][t];
        r.x += q.x; r.y += q.y; r.z += q.z; r.w += q.w;
    }
    ((f4*)part)[((size_t)sz * B_DIM + b) * 256 + t] = r;

    if (t < S_CHUNK)
        ex_buf[(size_t)(s0 + t) * B_DIM + b] = s_ex[t];

    if (w == 0) {
        float v = s_ex[lane];
        #pragma unroll
        for (int off = 32; off; off >>= 1) v += __shfl_xor(v, off);
        if (lane == 0) psum[sz * B_DIM + b] = v;
    }
}

// ---------------------------------------------------------------------------
// Kernel 3 (finalize): blocks 0..255: eij = ex_buf * inv_sum[b]
//                      blocks 256..511: attend = (sum_sz part) * inv_sum[b]
// ---------------------------------------------------------------------------
__global__ __launch_bounds__(256) void finalize_kernel(
    const float* __restrict__ ex_buf, const float* __restrict__ part,
    const float* __restrict__ psum,
    float* __restrict__ eij_out, float* __restrict__ att_out)
{
    const int blk = blockIdx.x;
    const int t = threadIdx.x;
    if (blk < 256) {
        int idx = blk * 256 + t;           // over [S][B]
        int b = idx & 63;
        float ssum = 0.f;
        #pragma unroll
        for (int sz = 0; sz < SSPLIT; ++sz) ssum += psum[sz * B_DIM + b];
        eij_out[idx] = ex_buf[idx] * (1.0f / ssum);
    } else {
        int idx = (blk - 256) * 256 + t;   // over [B][1024]
        int b = idx >> 10;
        float ssum = 0.f;
        #pragma unroll
        for (int sz = 0; sz < SSPLIT; ++sz) ssum += psum[sz * B_DIM + b];
        float acc = 0.f;
        #pragma unroll
        for (int sz = 0; sz < SSPLIT; ++sz) acc += part[(size_t)sz * 65536 + idx];
        att_out[idx] = acc * (1.0f / ssum);
    }
}

// ---------------------------------------------------------------------------
extern "C" void kernel_launch(void* const* d_in, const int* in_sizes, int n_in,
                              void* d_out, int out_size, void* d_ws, size_t ws_size,
                              hipStream_t stream) {
    const float* s_tm1   = (const float*)d_in[0];  // [64][1024]
    const float* xs_h    = (const float*)d_in[1];  // [1024][64][1024]
    const float* uh      = (const float*)d_in[2];  // [1024][64][1024]
    const float* xs_mask = (const float*)d_in[3];  // [1024][64]
    const float* sa_w    = (const float*)d_in[4];  // [1024][1024]
    const float* sa_b    = (const float*)d_in[5];  // [1024]
    const float* a1_w    = (const float*)d_in[6];  // [1][1024]
    // d_in[7] = a1_b: global constant shift -> cancels in softmax.

    float* eij_out = (float*)d_out;                 // [S][B]
    float* att_out = (float*)d_out + S_DIM * B_DIM; // [B][1024]

    float* part_gemm = (float*)d_ws;                               // 16*64*1024
    float* ksa       = part_gemm + (size_t)KSPLIT * B_DIM * 1024;  // 64*1024
    float* ex_buf    = ksa + 65536;                                // [S][B]
    float* part_att  = ex_buf + 65536;                             // 16*64*1024
    float* psum      = part_att + (size_t)SSPLIT * B_DIM * 1024;   // 16*64

    gemm_partial_kernel<<<dim3(A_DIM / A_TILE, KSPLIT), 256, 0, stream>>>(s_tm1, sa_w, part_gemm);
    gemm_reduce_kernel<<<65536 / 256, 256, 0, stream>>>(part_gemm, sa_b, ksa);
    fused_kernel<<<dim3(B_DIM, SSPLIT), 256, 0, stream>>>(uh, xs_h, ksa, a1_w, xs_mask,
                                                          ex_buf, psum, part_att);
    finalize_kernel<<<512, 256, 0, stream>>>(ex_buf, part_att, psum, eij_out, att_out);
}